// Round 4
// baseline (119.737 us; speedup 1.0000x reference)
//
#include <hip/hip_runtime.h>

// CostConcatenation: out[b,d,h,w, 0:16] = left[b,h,w,:]        (if valid else 0)
//                    out[b,d,h,w,16:32] = right[b,h,w-disp,:]  (if valid else 0)
// disp = d - 112 ; idx = w - disp = w + (112 - d) ; valid = 0<=idx<W
// Output (B, D, H, W, 2C) fp32 = 604 MB -> pure write-BW bound (~90 us floor
// at the 6.8 TB/s the fill kernel demonstrates).
//
// R4: d-tiling. One block handles DT=16 d-values for one (b,h) row.
//  - Since 256 % 8 == 0, each thread's 6 positions share c4 = tid&7:
//    a thread is ENTIRELY left-half (c4<4) or right-half (c4>=4).
//  - Left threads hoist their 6 loads out of the d-loop (d-invariant values;
//    only the valid mask changes -> cndmask per store).
//  - Right threads re-read a 12 KB rrow that stays L1-resident across the
//    16 d-iterations (was: L2 round-trip per block in R3).

constexpr int B_ = 2;
constexpr int H_ = 96;
constexpr int W_ = 192;
constexpr int D_ = 128;
constexpr int DT = 16;                 // d-values per block
constexpr int NJ = (W_ * 8) / 256;     // 6 float4 per thread per d

typedef float v4f __attribute__((ext_vector_type(4)));

__global__ __launch_bounds__(256) void cost_concat_kernel(
    const v4f* __restrict__ left,
    const v4f* __restrict__ right,
    v4f* __restrict__ out)
{
    const int h  = blockIdx.x;
    const int d0 = blockIdx.y * DT;
    const int b  = blockIdx.z;
    const int tid = threadIdx.x;

    const int rowBase = (b * H_ + h) * (W_ * 4);   // float4 units
    const v4f* __restrict__ lrow = left  + rowBase;
    const v4f* __restrict__ rrow = right + rowBase;

    const bool isLeft = (tid & 7) < 4;
    const int  c      = tid & 3;                   // float4 slot within the half

    // Preload left-half values (d-invariant) and cell indices.
    int ws[NJ];
    v4f lv[NJ];
    #pragma unroll
    for (int k = 0; k < NJ; ++k) {
        const int j = tid + 256 * k;
        ws[k] = j >> 3;
        lv[k] = (v4f)(0.f);
        if (isLeft) lv[k] = lrow[ws[k] * 4 + c];
    }

    // out index (b,d,h,w,c4): base for (b,d0,h); d-stride = H*W*8 float4
    long long outBase =
        (((long long)(b * D_ + d0)) * H_ + h) * (long long)(W_ * 8);
    const long long dStride = (long long)H_ * (W_ * 8);

    for (int dd = 0; dd < DT; ++dd) {
        const int shift = 112 - (d0 + dd);         // idx = w + shift
        v4f* __restrict__ orow = out + outBase;

        #pragma unroll
        for (int k = 0; k < NJ; ++k) {
            const int idx = ws[k] + shift;
            const bool valid = (unsigned)idx < (unsigned)W_;

            v4f v = (v4f)(0.f);
            if (isLeft) {
                if (valid) v = lv[k];              // cndmask on preloaded value
            } else {
                if (valid) v = rrow[idx * 4 + c];  // L1-resident across dd
            }
            __builtin_nontemporal_store(v, orow + (tid + 256 * k));
        }
        outBase += dStride;
    }
}

extern "C" void kernel_launch(void* const* d_in, const int* in_sizes, int n_in,
                              void* d_out, int out_size, void* d_ws, size_t ws_size,
                              hipStream_t stream)
{
    const v4f* left  = (const v4f*)d_in[0];
    const v4f* right = (const v4f*)d_in[1];
    v4f* out = (v4f*)d_out;

    dim3 grid(H_, D_ / DT, B_);   // 96 * 8 * 2 = 1536 blocks, 384 KB written each
    cost_concat_kernel<<<grid, 256, 0, stream>>>(left, right, out);
}